// Round 4
// baseline (802.147 us; speedup 1.0000x reference)
//
#include <hip/hip_runtime.h>
#include <math.h>

#define NEG_SLOPE 0.2f
#define LN_EPS 1e-5f

typedef __attribute__((ext_vector_type(8))) short bf16x8;
typedef __attribute__((ext_vector_type(4))) float f32x4;

__device__ __forceinline__ float lrelu(float v){ return v > 0.f ? v : NEG_SLOPE * v; }
__device__ __forceinline__ float eluf (float v){ return v > 0.f ? v : expm1f(v); }

__device__ __forceinline__ unsigned short f2bf(float f){
    unsigned x = __float_as_uint(f);
    unsigned r = (x + 0x7fffu + ((x >> 16) & 1u)) >> 16;   // round-nearest-even
    return (unsigned short)r;
}
__device__ __forceinline__ float bf_lo(unsigned u){ return __uint_as_float(u << 16); }
__device__ __forceinline__ float bf_hi(unsigned u){ return __uint_as_float(u & 0xffff0000u); }

// ---------------- bucketed CSR build ----------------
// bucket b = dst >> 6 : 64 nodes, ~1024 edges. Packed edge: (dst&63)<<26 | src
// (requires src < 2^26 and N fixed; harness N=100000).

__global__ void k_bcount(const int* __restrict__ dst, int* __restrict__ bcnt, int E){
    int e = blockIdx.x * 256 + threadIdx.x;
    if (e < E) atomicAdd(&bcnt[dst[e] >> 6], 1);
}

__global__ void k_chunk_sum(const int* __restrict__ deg, int* __restrict__ partial, int N){
    __shared__ int lds[256];
    int t = threadIdx.x;
    int v = blockIdx.x * 256 + t;
    lds[t] = (v < N) ? deg[v] : 0;
    __syncthreads();
    for (int s = 128; s > 0; s >>= 1){
        if (t < s) lds[t] += lds[t + s];
        __syncthreads();
    }
    if (t == 0) partial[blockIdx.x] = lds[0];
}

__global__ void k_scan_partial(int* __restrict__ partial, int n){
    __shared__ int lds[512];
    int t = threadIdx.x;
    int x = (t < n) ? partial[t] : 0;
    lds[t] = x;
    __syncthreads();
    for (int s = 1; s < 512; s <<= 1){
        int a = (t >= s) ? lds[t - s] : 0;
        __syncthreads();
        lds[t] += a;
        __syncthreads();
    }
    if (t < n) partial[t] = lds[t] - x;   // exclusive
}

__global__ void k_scan_final(const int* __restrict__ deg, const int* __restrict__ partial,
                             int* __restrict__ row_ptr, int* __restrict__ cursor, int N){
    __shared__ int lds[256];
    int t = threadIdx.x;
    int v = blockIdx.x * 256 + t;
    int x = (v < N) ? deg[v] : 0;
    lds[t] = x;
    __syncthreads();
    for (int s = 1; s < 256; s <<= 1){
        int a = (t >= s) ? lds[t - s] : 0;
        __syncthreads();
        lds[t] += a;
        __syncthreads();
    }
    int rp = partial[blockIdx.x] + lds[t] - x;  // exclusive prefix
    if (v < N){
        row_ptr[v] = rp;
        cursor[v]  = rp;
        if (v == N - 1) row_ptr[N] = rp + x;
    }
}

__global__ void k_bscatter(const int* __restrict__ src, const int* __restrict__ dst,
                           int* __restrict__ bcur, unsigned* __restrict__ ebuf, int E){
    int e = blockIdx.x * 256 + threadIdx.x;
    if (e < E){
        int d = dst[e];
        int pos = atomicAdd(&bcur[d >> 6], 1);
        ebuf[pos] = ((unsigned)(d & 63) << 26) | (unsigned)src[e];
    }
}

// one wave per bucket: local degree count -> wave-scan -> row_ptr + LDS-cursor fill
__global__ __launch_bounds__(256) void k_bfill(
    const unsigned* __restrict__ ebuf, const int* __restrict__ boff,
    int* __restrict__ row_ptr, int* __restrict__ col, int N, int NBUK, int E)
{
    __shared__ int scnt[4][64];
    int t = threadIdx.x, lane = t & 63, w = t >> 6;
    int b = blockIdx.x * 4 + w;
    bool act = b < NBUK;
    if (t == 0 && blockIdx.x == 0) row_ptr[N] = E;
    scnt[w][lane] = 0;
    __syncthreads();
    int ebeg = 0, eend = 0;
    if (act){ ebeg = boff[b]; eend = boff[b + 1]; }
    for (int j = ebeg + lane; j < eend; j += 64)
        atomicAdd(&scnt[w][ebuf[j] >> 26], 1);
    __syncthreads();
    int deg = scnt[w][lane];
    int incl = deg;
    #pragma unroll
    for (int k = 1; k < 64; k <<= 1){
        int up = __shfl_up(incl, k);
        if (lane >= k) incl += up;
    }
    int excl = incl - deg;
    int base = act ? boff[b] : 0;
    int v = b * 64 + lane;
    if (act && v < N) row_ptr[v] = base + excl;
    __syncthreads();
    scnt[w][lane] = base + excl;
    __syncthreads();
    for (int j = ebeg + lane; j < eend; j += 64){
        unsigned u = ebuf[j];
        int pos = atomicAdd(&scnt[w][u >> 26], 1);
        col[pos] = (int)(u & 0x03FFFFFFu);
    }
}

// ---------------- layer 1 linear: x[N,3] @ W1[3,128] -> bf16, e_src/e_dst ----------------

__global__ __launch_bounds__(256) void k_lin1(
    const float* __restrict__ x, const float* __restrict__ W1,
    const float* __restrict__ asrc, const float* __restrict__ adst,
    unsigned* __restrict__ hlinb, float* __restrict__ es, float* __restrict__ ed, int N)
{
    __shared__ float sW[384], sA[128], sB[128];
    int t = threadIdx.x;
    for (int i = t; i < 384; i += 256) sW[i] = W1[i];
    for (int i = t; i < 128; i += 256){ sA[i] = asrc[i]; sB[i] = adst[i]; }
    __syncthreads();
    int lane = t & 63;
    int v = blockIdx.x * 4 + (t >> 6);
    if (v >= N) return;
    float x0 = x[(size_t)v*3], x1 = x[(size_t)v*3+1], x2 = x[(size_t)v*3+2];
    int c = lane * 2;
    float h0 = x0*sW[c  ] + x1*sW[128+c  ] + x2*sW[256+c  ];
    float h1 = x0*sW[c+1] + x1*sW[128+c+1] + x2*sW[256+c+1];
    hlinb[(size_t)v*64 + lane] = (unsigned)f2bf(h0) | ((unsigned)f2bf(h1) << 16);
    int hsel = lane >> 4;
    float ts = h0*sA[c] + h1*sA[c+1];
    float td = h0*sB[c] + h1*sB[c+1];
    #pragma unroll
    for (int m = 8; m >= 1; m >>= 1){
        ts += __shfl_xor(ts, m); td += __shfl_xor(td, m);
    }
    if ((lane & 15) == 0){
        es[(size_t)v*4 + hsel] = ts;
        ed[(size_t)v*4 + hsel] = td;
    }
}

// ---------------- layer 1: fused single-pass attention + agg + bias + ELU + LN -> bf16 ----------------

__global__ __launch_bounds__(256) void k_agg1(
    const unsigned* __restrict__ hlinb,     // [N][64] bf16x2
    const float* __restrict__ es, const float* __restrict__ ed,
    const int* __restrict__ row_ptr, const int* __restrict__ col,
    const float* __restrict__ b1, const float* __restrict__ g1, const float* __restrict__ be1,
    unsigned* __restrict__ h1b, int N)
{
    __shared__ float sp[4][4][68];   // [wave][head][edge], padded
    int t = threadIdx.x, lane = t & 63, w = t >> 6;
    int v = blockIdx.x * 4 + w;
    if (v >= N) return;
    float4 edv = *(const float4*)(ed + (size_t)v*4);
    float4 esv = *(const float4*)(es + (size_t)v*4);
    int hsel = lane >> 4;
    float dsel = hsel==0 ? edv.x : hsel==1 ? edv.y : hsel==2 ? edv.z : edv.w;
    float esel = hsel==0 ? esv.x : hsel==1 ? esv.y : hsel==2 ? esv.z : esv.w;
    float pself = __expf(lrelu(esel + dsel));          // no max-shift: logits are O(1)
    unsigned uself = hlinb[(size_t)v*64 + lane];
    float acc0 = pself * bf_lo(uself);
    float acc1 = pself * bf_hi(uself);
    float sum_p = pself;
    int beg = row_ptr[v], end = row_ptr[v+1];
    for (int base = beg; base < end; base += 64){
        int cnt = min(64, end - base);
        int sreg = 0;
        if (lane < cnt){
            sreg = col[base + lane];
            float4 q = *(const float4*)(es + (size_t)sreg*4);
            sp[w][0][lane] = __expf(lrelu(q.x + edv.x));
            sp[w][1][lane] = __expf(lrelu(q.y + edv.y));
            sp[w][2][lane] = __expf(lrelu(q.z + edv.z));
            sp[w][3][lane] = __expf(lrelu(q.w + edv.w));
        }
        asm volatile("s_waitcnt lgkmcnt(0)" ::: "memory");
        for (int jj = 0; jj < cnt; ++jj){
            int s = __builtin_amdgcn_readlane(sreg, jj);
            float p = sp[w][hsel][jj];
            unsigned u = hlinb[(size_t)s*64 + lane];
            sum_p += p;
            acc0 += p * bf_lo(u);
            acc1 += p * bf_hi(u);
        }
    }
    float inv = 1.f / (sum_p + 1e-16f);
    int c = lane * 2;
    float2 bb = *(const float2*)(b1 + c);
    float oA = eluf(acc0 * inv + bb.x);
    float oB = eluf(acc1 * inv + bb.y);
    float su = oA + oB;
    #pragma unroll
    for (int k = 32; k >= 1; k >>= 1) su += __shfl_xor(su, k);
    float mean = su * (1.f/128.f);
    float aA = oA - mean, aB = oB - mean;
    float vs = aA*aA + aB*aB;
    #pragma unroll
    for (int k = 32; k >= 1; k >>= 1) vs += __shfl_xor(vs, k);
    float rstd = rsqrtf(vs * (1.f/128.f) + LN_EPS);
    float2 gg = *(const float2*)(g1 + c);
    float2 ee = *(const float2*)(be1 + c);
    float rx = aA*rstd*gg.x + ee.x, ry = aB*rstd*gg.y + ee.y;
    h1b[(size_t)v*64 + lane] = (unsigned)f2bf(rx) | ((unsigned)f2bf(ry) << 16);
}

// ---------------- layer 2 linear via MFMA: h1b[N,128]bf16 @ W2[128,64] ----------------

__global__ __launch_bounds__(256) void k_lin2(
    const unsigned short* __restrict__ h1b,   // [N][128] bf16
    const float* __restrict__ W2,             // [128][64] fp32
    const float* __restrict__ asrc, const float* __restrict__ adst,
    unsigned short* __restrict__ hlin2b, float* __restrict__ es2, float* __restrict__ ed2, int N)
{
    int t = threadIdx.x, lane = t & 63, w = t >> 6;
    int vb = blockIdx.x * 64 + w * 16;
    if (vb >= N) return;
    int lo4 = lane & 15, hi4 = lane >> 4;

    int arow = vb + lo4; if (arow >= N) arow = N - 1;
    const unsigned short* ap = h1b + (size_t)arow*128 + hi4*8;
    bf16x8 a0 = *(const bf16x8*)(ap);
    bf16x8 a1 = *(const bf16x8*)(ap + 32);
    bf16x8 a2 = *(const bf16x8*)(ap + 64);
    bf16x8 a3 = *(const bf16x8*)(ap + 96);

    f32x4 acc[4];
    #pragma unroll
    for (int nt = 0; nt < 4; ++nt) acc[nt] = (f32x4){0.f, 0.f, 0.f, 0.f};

    #pragma unroll
    for (int nt = 0; nt < 4; ++nt){
        int cb = nt*16 + lo4;
        #pragma unroll
        for (int kt = 0; kt < 4; ++kt){
            const float* wp = W2 + (size_t)(kt*32 + hi4*8)*64 + cb;
            bf16x8 b;
            #pragma unroll
            for (int j = 0; j < 8; ++j) b[j] = (short)f2bf(wp[(size_t)j*64]);
            bf16x8 a = (kt==0) ? a0 : (kt==1) ? a1 : (kt==2) ? a2 : a3;
            acc[nt] = __builtin_amdgcn_mfma_f32_16x16x32_bf16(a, b, acc[nt], 0, 0, 0);
        }
    }

    float sa0 = asrc[lo4], sa1 = asrc[16+lo4], sa2 = asrc[32+lo4], sa3 = asrc[48+lo4];
    float sb0 = adst[lo4], sb1 = adst[16+lo4], sb2 = adst[32+lo4], sb3 = adst[48+lo4];

    #pragma unroll
    for (int reg = 0; reg < 4; ++reg){
        int nr = vb + hi4*4 + reg;
        bool ok = nr < N;
        float c0 = acc[0][reg], c1 = acc[1][reg], c2 = acc[2][reg], c3 = acc[3][reg];
        if (ok){
            unsigned short* hp = hlin2b + (size_t)nr*64 + lo4;
            hp[ 0] = f2bf(c0);
            hp[16] = f2bf(c1);
            hp[32] = f2bf(c2);
            hp[48] = f2bf(c3);
        }
        float ps0 = c0*sa0 + c1*sa1, ps1 = c2*sa2 + c3*sa3;
        float pd0 = c0*sb0 + c1*sb1, pd1 = c2*sb2 + c3*sb3;
        #pragma unroll
        for (int m = 8; m >= 1; m >>= 1){
            ps0 += __shfl_xor(ps0, m); ps1 += __shfl_xor(ps1, m);
            pd0 += __shfl_xor(pd0, m); pd1 += __shfl_xor(pd1, m);
        }
        if (ok && lo4 == 0){
            float2 e; e.x = ps0; e.y = ps1;
            float2 d; d.x = pd0; d.y = pd1;
            *(float2*)(es2 + (size_t)nr*2) = e;
            *(float2*)(ed2 + (size_t)nr*2) = d;
        }
    }
}

// ---------------- layer 2: fused single-pass attn+agg + head-mean + ELU + skip + LN ----------------

__global__ __launch_bounds__(256) void k_agg2(
    const unsigned short* __restrict__ hlin2b,   // [N][64] bf16
    const float* __restrict__ es2, const float* __restrict__ ed2,
    const int* __restrict__ row_ptr, const int* __restrict__ col,
    const float* __restrict__ x, const float* __restrict__ Wskip, const float* __restrict__ bskip,
    const float* __restrict__ b2, const float* __restrict__ g2, const float* __restrict__ be2,
    float* __restrict__ h2, int N)
{
    __shared__ float sp[4][2][68];
    int t = threadIdx.x, lane = t & 63, w = t >> 6;
    int v = blockIdx.x * 4 + w;
    if (v >= N) return;
    float2 edv = *(const float2*)(ed2 + (size_t)v*2);
    float2 esv = *(const float2*)(es2 + (size_t)v*2);
    int hsel = lane >> 5;
    float dsel = hsel ? edv.y : edv.x;
    float esel = hsel ? esv.y : esv.x;
    float pself = __expf(lrelu(esel + dsel));
    float acc = pself * __uint_as_float(((unsigned)hlin2b[(size_t)v*64 + lane]) << 16);
    float sum_p = pself;
    int beg = row_ptr[v], end = row_ptr[v+1];
    for (int base = beg; base < end; base += 64){
        int cnt = min(64, end - base);
        int sreg = 0;
        if (lane < cnt){
            sreg = col[base + lane];
            float2 q = *(const float2*)(es2 + (size_t)sreg*2);
            sp[w][0][lane] = __expf(lrelu(q.x + edv.x));
            sp[w][1][lane] = __expf(lrelu(q.y + edv.y));
        }
        asm volatile("s_waitcnt lgkmcnt(0)" ::: "memory");
        for (int jj = 0; jj < cnt; ++jj){
            int s = __builtin_amdgcn_readlane(sreg, jj);
            float p = sp[w][hsel][jj];
            unsigned short u = hlin2b[(size_t)s*64 + lane];
            sum_p += p;
            acc += p * __uint_as_float(((unsigned)u) << 16);
        }
    }
    acc /= (sum_p + 1e-16f);
    float other = __shfl(acc, lane ^ 32);
    if (lane < 32){
        float o = 0.5f * (acc + other) + b2[lane];
        o = eluf(o);
        float sk = x[(size_t)v*3]*Wskip[lane] + x[(size_t)v*3+1]*Wskip[32+lane]
                 + x[(size_t)v*3+2]*Wskip[64+lane] + bskip[lane];
        float z = o + sk;
        float su = z;
        #pragma unroll
        for (int k = 16; k >= 1; k >>= 1) su += __shfl_xor(su, k);
        float mean = su * (1.f/32.f);
        float d = z - mean;
        float vs = d*d;
        #pragma unroll
        for (int k = 16; k >= 1; k >>= 1) vs += __shfl_xor(vs, k);
        float rstd = rsqrtf(vs * (1.f/32.f) + LN_EPS);
        h2[(size_t)v*32 + lane] = d*rstd*g2[lane] + be2[lane];
    }
}

// ---------------- pooling: per-graph mean/max/std (batch sorted) + projection ----------------

__global__ __launch_bounds__(256) void k_pool(
    const float* __restrict__ h2, const int* __restrict__ batch,
    const float* __restrict__ Wp, const float* __restrict__ bp,
    float* __restrict__ out, int N)
{
    int g = blockIdx.x; int t = threadIdx.x;
    __shared__ int sBeg, sEnd;
    if (t == 0){
        int lo = 0, hi = N;
        while (lo < hi){ int mid = (lo+hi) >> 1; if (batch[mid] < g) lo = mid+1; else hi = mid; }
        sBeg = lo;
        lo = sBeg; hi = N;
        while (lo < hi){ int mid = (lo+hi) >> 1; if (batch[mid] < g+1) lo = mid+1; else hi = mid; }
        sEnd = lo;
    }
    __syncthreads();
    int beg = sBeg, end = sEnd;
    int ch = t & 31, grp = t >> 5;
    float sum = 0.f, sq = 0.f, mx = -INFINITY;
    for (int i = beg + grp; i < end; i += 8){
        float val = h2[(size_t)i*32 + ch];
        sum += val; sq += val*val; mx = fmaxf(mx, val);
    }
    __shared__ float lsum[256], lsq[256], lmx[256];
    lsum[t] = sum; lsq[t] = sq; lmx[t] = mx;
    __syncthreads();
    for (int s = 4; s >= 1; s >>= 1){
        if (grp < s){
            lsum[t] += lsum[t + s*32];
            lsq [t] += lsq [t + s*32];
            lmx [t]  = fmaxf(lmx[t], lmx[t + s*32]);
        }
        __syncthreads();
    }
    __shared__ float feat[96];
    if (t < 32){
        float cnt = fmaxf((float)(end - beg), 1.f);
        float mean = lsum[t] / cnt;
        float var  = lsq[t] / cnt - mean*mean;
        feat[t]      = mean;
        feat[32 + t] = lmx[t];
        feat[64 + t] = sqrtf(fmaxf(var, 0.f));
    }
    __syncthreads();
    if (t < 48){
        float acc = bp[t];
        #pragma unroll 8
        for (int k = 0; k < 96; ++k) acc += feat[k] * Wp[k*48 + t];
        out[(size_t)g*48 + t] = acc;
    }
}

// ---------------- launcher ----------------

extern "C" void kernel_launch(void* const* d_in, const int* in_sizes, int n_in,
                              void* d_out, int out_size, void* d_ws, size_t ws_size,
                              hipStream_t stream)
{
    const float* x     = (const float*)d_in[0];
    const int*   ei    = (const int*)  d_in[1];
    const int*   batch = (const int*)  d_in[2];
    const float* W1    = (const float*)d_in[3];
    const float* as1   = (const float*)d_in[4];
    const float* ad1   = (const float*)d_in[5];
    const float* b1    = (const float*)d_in[6];
    const float* W2    = (const float*)d_in[7];
    const float* as2   = (const float*)d_in[8];
    const float* ad2   = (const float*)d_in[9];
    const float* b2    = (const float*)d_in[10];
    const float* Wskip = (const float*)d_in[11];
    const float* bskip = (const float*)d_in[12];
    const float* g1    = (const float*)d_in[13];
    const float* be1   = (const float*)d_in[14];
    const float* g2    = (const float*)d_in[15];
    const float* be2   = (const float*)d_in[16];
    const float* Wp    = (const float*)d_in[17];
    const float* bp    = (const float*)d_in[18];

    int N = in_sizes[0] / 3;
    int E = in_sizes[1] / 2;
    int B = out_size / 48;
    const int* src = ei;
    const int* dst = ei + E;
    int NBUK = (N + 63) / 64;

    char* w = (char*)d_ws;
    auto alloc = [&](size_t bytes) -> char* {
        char* p = w; w += (bytes + 255) & ~(size_t)255; return p;
    };
    int*   row_ptr = (int*)  alloc((size_t)(N+1)*4);
    int*   bcnt    = (int*)  alloc((size_t)NBUK*4);
    int*   boff    = (int*)  alloc((size_t)(NBUK+1)*4);
    int*   bcur    = (int*)  alloc((size_t)NBUK*4);
    int*   partial = (int*)  alloc(4*1024);
    int*   col     = (int*)  alloc((size_t)E*4);
    unsigned* hlinb= (unsigned*)alloc((size_t)N*64*4); // L1: bf16x2[N][64]; L2 reuses as u16[N][64]
    float* es      = (float*)alloc((size_t)N*4*4);
    float* ed      = (float*)alloc((size_t)N*4*4);
    unsigned* h1b  = (unsigned*)alloc((size_t)N*64*4); // bf16[N][128]
    float* h2      = (float*)alloc((size_t)N*32*4);
    unsigned* ebuf = (unsigned*)h2;                    // alias: ebuf dead before agg2 writes h2
    (void)ws_size;

    hipMemsetAsync(bcnt, 0, (size_t)NBUK*4, stream);

    int eb   = (E + 255) / 256;
    int nchb = (NBUK + 255) / 256;
    int nb   = (N + 3) / 4;
    int nb2  = (N + 63) / 64;

    k_bcount      <<<eb, 256, 0, stream>>>(dst, bcnt, E);
    k_chunk_sum   <<<nchb, 256, 0, stream>>>(bcnt, partial, NBUK);
    k_scan_partial<<<1, 512, 0, stream>>>(partial, nchb);
    k_scan_final  <<<nchb, 256, 0, stream>>>(bcnt, partial, boff, bcur, NBUK);
    k_bscatter    <<<eb, 256, 0, stream>>>(src, dst, bcur, ebuf, E);
    k_bfill       <<<(NBUK + 3) / 4, 256, 0, stream>>>(ebuf, boff, row_ptr, col, N, NBUK, E);

    k_lin1 <<<nb, 256, 0, stream>>>(x, W1, as1, ad1, hlinb, es, ed, N);
    k_agg1 <<<nb, 256, 0, stream>>>(hlinb, es, ed, row_ptr, col, b1, g1, be1, h1b, N);
    k_lin2 <<<nb2, 256, 0, stream>>>((const unsigned short*)h1b, W2, as2, ad2,
                                     (unsigned short*)hlinb, es, ed, N);
    k_agg2 <<<nb, 256, 0, stream>>>((unsigned short*)hlinb, es, ed, row_ptr, col,
                                    x, Wskip, bskip, b2, g2, be2, h2, N);
    k_pool <<<B, 256, 0, stream>>>(h2, batch, Wp, bp, (float*)d_out, N);
}

// Round 5
// 388.729 us; speedup vs baseline: 2.0635x; 2.0635x over previous
//
#include <hip/hip_runtime.h>
#include <math.h>

#define NEG_SLOPE 0.2f
#define LN_EPS 1e-5f
#define NWG 48          // scatter workgroups; hist = [NB][NWG], NB*NWG must scan in <=512*256

typedef __attribute__((ext_vector_type(8))) short bf16x8;
typedef __attribute__((ext_vector_type(4))) float f32x4;

__device__ __forceinline__ float lrelu(float v){ return v > 0.f ? v : NEG_SLOPE * v; }
__device__ __forceinline__ float eluf (float v){ return v > 0.f ? v : expm1f(v); }

__device__ __forceinline__ unsigned short f2bf(float f){
    unsigned x = __float_as_uint(f);
    unsigned r = (x + 0x7fffu + ((x >> 16) & 1u)) >> 16;   // round-nearest-even
    return (unsigned short)r;
}
__device__ __forceinline__ float bf_lo(unsigned u){ return __uint_as_float(u << 16); }
__device__ __forceinline__ float bf_hi(unsigned u){ return __uint_as_float(u & 0xffff0000u); }

// ---------------- bucketed CSR build, atomic-free scatter ----------------
// bucket b = dst >> 6 (64 nodes, ~1024 edges). Packed edge: (dst&63)<<26 | src.
// hist[b*NWG + w] = #edges of bucket b in wg w's chunk -> exclusive scan gives
// each (wg,bucket) a private contiguous output run (no global atomics, no
// cross-XCD shared tail lines).

__global__ __launch_bounds__(512) void k_hist(
    const int* __restrict__ dst, int* __restrict__ hist, int E, int NB, int chunk)
{
    __shared__ int cnt[2048];
    int t = threadIdx.x, w = blockIdx.x;
    for (int i = t; i < NB; i += 512) cnt[i] = 0;
    __syncthreads();
    int e0 = w * chunk, e1 = min(E, e0 + chunk);
    for (int e = e0 + t; e < e1; e += 512)
        atomicAdd(&cnt[dst[e] >> 6], 1);
    __syncthreads();
    for (int i = t; i < NB; i += 512)
        hist[i * NWG + w] = cnt[i];
}

__global__ void k_chunk_sum(const int* __restrict__ data, int* __restrict__ partial, int M){
    __shared__ int lds[256];
    int t = threadIdx.x;
    int v = blockIdx.x * 256 + t;
    lds[t] = (v < M) ? data[v] : 0;
    __syncthreads();
    for (int s = 128; s > 0; s >>= 1){
        if (t < s) lds[t] += lds[t + s];
        __syncthreads();
    }
    if (t == 0) partial[blockIdx.x] = lds[0];
}

__global__ void k_scan_partial(int* __restrict__ partial, int n){
    __shared__ int lds[512];
    int t = threadIdx.x;
    int x = (t < n) ? partial[t] : 0;
    lds[t] = x;
    __syncthreads();
    for (int s = 1; s < 512; s <<= 1){
        int a = (t >= s) ? lds[t - s] : 0;
        __syncthreads();
        lds[t] += a;
        __syncthreads();
    }
    if (t < n) partial[t] = lds[t] - x;   // exclusive
}

__global__ void k_scan_apply(int* __restrict__ data, const int* __restrict__ partial, int M){
    __shared__ int lds[256];
    int t = threadIdx.x;
    int v = blockIdx.x * 256 + t;
    int x = (v < M) ? data[v] : 0;
    lds[t] = x;
    __syncthreads();
    for (int s = 1; s < 256; s <<= 1){
        int a = (t >= s) ? lds[t - s] : 0;
        __syncthreads();
        lds[t] += a;
        __syncthreads();
    }
    if (v < M) data[v] = partial[blockIdx.x] + lds[t] - x;   // exclusive
}

__global__ __launch_bounds__(512) void k_pscatter(
    const int* __restrict__ src, const int* __restrict__ dst,
    const int* __restrict__ shist, unsigned* __restrict__ ebuf, int E, int NB, int chunk)
{
    __shared__ int cur[2048];
    int t = threadIdx.x, w = blockIdx.x;
    for (int i = t; i < NB; i += 512) cur[i] = shist[i * NWG + w];
    __syncthreads();
    int e0 = w * chunk, e1 = min(E, e0 + chunk);
    for (int e = e0 + t; e < e1; e += 512){
        int d = dst[e];
        int pos = atomicAdd(&cur[d >> 6], 1);
        ebuf[pos] = ((unsigned)(d & 63) << 26) | (unsigned)src[e];
    }
}

// one wave per bucket: local degree count -> wave-scan -> row_ptr + LDS-cursor fill
__global__ __launch_bounds__(256) void k_bfill(
    const unsigned* __restrict__ ebuf, const int* __restrict__ shist,
    int* __restrict__ row_ptr, int* __restrict__ col, int N, int NB, int E)
{
    __shared__ int scnt[4][64];
    int t = threadIdx.x, lane = t & 63, w = t >> 6;
    int b = blockIdx.x * 4 + w;
    bool act = b < NB;
    if (t == 0 && blockIdx.x == 0) row_ptr[N] = E;
    scnt[w][lane] = 0;
    __syncthreads();
    int ebeg = 0, eend = 0;
    if (act){
        ebeg = shist[b * NWG];
        eend = (b + 1 < NB) ? shist[(b + 1) * NWG] : E;
    }
    for (int j = ebeg + lane; j < eend; j += 64)
        atomicAdd(&scnt[w][ebuf[j] >> 26], 1);
    __syncthreads();
    int deg = scnt[w][lane];
    int incl = deg;
    #pragma unroll
    for (int k = 1; k < 64; k <<= 1){
        int up = __shfl_up(incl, k);
        if (lane >= k) incl += up;
    }
    int excl = incl - deg;
    int base = act ? ebeg : 0;
    int v = b * 64 + lane;
    if (act && v < N) row_ptr[v] = base + excl;
    __syncthreads();
    scnt[w][lane] = base + excl;
    __syncthreads();
    for (int j = ebeg + lane; j < eend; j += 64){
        unsigned u = ebuf[j];
        int pos = atomicAdd(&scnt[w][u >> 26], 1);
        col[pos] = (int)(u & 0x03FFFFFFu);
    }
}

// ---------------- layer 1 linear: x[N,3] @ W1[3,128] -> bf16, e_src/e_dst ----------------

__global__ __launch_bounds__(256) void k_lin1(
    const float* __restrict__ x, const float* __restrict__ W1,
    const float* __restrict__ asrc, const float* __restrict__ adst,
    unsigned* __restrict__ hlinb, float* __restrict__ es, float* __restrict__ ed, int N)
{
    __shared__ float sW[384], sA[128], sB[128];
    int t = threadIdx.x;
    for (int i = t; i < 384; i += 256) sW[i] = W1[i];
    for (int i = t; i < 128; i += 256){ sA[i] = asrc[i]; sB[i] = adst[i]; }
    __syncthreads();
    int lane = t & 63;
    int v = blockIdx.x * 4 + (t >> 6);
    if (v >= N) return;
    float x0 = x[(size_t)v*3], x1 = x[(size_t)v*3+1], x2 = x[(size_t)v*3+2];
    int c = lane * 2;
    float h0 = x0*sW[c  ] + x1*sW[128+c  ] + x2*sW[256+c  ];
    float h1 = x0*sW[c+1] + x1*sW[128+c+1] + x2*sW[256+c+1];
    hlinb[(size_t)v*64 + lane] = (unsigned)f2bf(h0) | ((unsigned)f2bf(h1) << 16);
    int hsel = lane >> 4;
    float ts = h0*sA[c] + h1*sA[c+1];
    float td = h0*sB[c] + h1*sB[c+1];
    #pragma unroll
    for (int m = 8; m >= 1; m >>= 1){
        ts += __shfl_xor(ts, m); td += __shfl_xor(td, m);
    }
    if ((lane & 15) == 0){
        es[(size_t)v*4 + hsel] = ts;
        ed[(size_t)v*4 + hsel] = td;
    }
}

// ---------------- layer 1: fused single-pass attention + agg + bias + ELU + LN -> bf16 ----------------

__global__ __launch_bounds__(256) void k_agg1(
    const unsigned* __restrict__ hlinb,     // [N][64] bf16x2
    const float* __restrict__ es, const float* __restrict__ ed,
    const int* __restrict__ row_ptr, const int* __restrict__ col,
    const float* __restrict__ b1, const float* __restrict__ g1, const float* __restrict__ be1,
    unsigned* __restrict__ h1b, int N)
{
    __shared__ float sp[4][4][68];   // [wave][head][edge], padded
    int t = threadIdx.x, lane = t & 63, w = t >> 6;
    int v = blockIdx.x * 4 + w;
    if (v >= N) return;
    float4 edv = *(const float4*)(ed + (size_t)v*4);
    float4 esv = *(const float4*)(es + (size_t)v*4);
    int hsel = lane >> 4;
    float dsel = hsel==0 ? edv.x : hsel==1 ? edv.y : hsel==2 ? edv.z : edv.w;
    float esel = hsel==0 ? esv.x : hsel==1 ? esv.y : hsel==2 ? esv.z : esv.w;
    float pself = __expf(lrelu(esel + dsel));          // no max-shift: logits are O(1)
    unsigned uself = hlinb[(size_t)v*64 + lane];
    float acc0 = pself * bf_lo(uself);
    float acc1 = pself * bf_hi(uself);
    float sum_p = pself;
    int beg = row_ptr[v], end = row_ptr[v+1];
    for (int base = beg; base < end; base += 64){
        int cnt = min(64, end - base);
        int sreg = 0;
        if (lane < cnt){
            sreg = col[base + lane];
            float4 q = *(const float4*)(es + (size_t)sreg*4);
            sp[w][0][lane] = __expf(lrelu(q.x + edv.x));
            sp[w][1][lane] = __expf(lrelu(q.y + edv.y));
            sp[w][2][lane] = __expf(lrelu(q.z + edv.z));
            sp[w][3][lane] = __expf(lrelu(q.w + edv.w));
        }
        asm volatile("s_waitcnt lgkmcnt(0)" ::: "memory");
        for (int jj = 0; jj < cnt; ++jj){
            int s = __builtin_amdgcn_readlane(sreg, jj);
            float p = sp[w][hsel][jj];
            unsigned u = hlinb[(size_t)s*64 + lane];
            sum_p += p;
            acc0 += p * bf_lo(u);
            acc1 += p * bf_hi(u);
        }
    }
    float inv = 1.f / (sum_p + 1e-16f);
    int c = lane * 2;
    float2 bb = *(const float2*)(b1 + c);
    float oA = eluf(acc0 * inv + bb.x);
    float oB = eluf(acc1 * inv + bb.y);
    float su = oA + oB;
    #pragma unroll
    for (int k = 32; k >= 1; k >>= 1) su += __shfl_xor(su, k);
    float mean = su * (1.f/128.f);
    float aA = oA - mean, aB = oB - mean;
    float vs = aA*aA + aB*aB;
    #pragma unroll
    for (int k = 32; k >= 1; k >>= 1) vs += __shfl_xor(vs, k);
    float rstd = rsqrtf(vs * (1.f/128.f) + LN_EPS);
    float2 gg = *(const float2*)(g1 + c);
    float2 ee = *(const float2*)(be1 + c);
    float rx = aA*rstd*gg.x + ee.x, ry = aB*rstd*gg.y + ee.y;
    h1b[(size_t)v*64 + lane] = (unsigned)f2bf(rx) | ((unsigned)f2bf(ry) << 16);
}

// ---------------- layer 2 linear via MFMA: h1b[N,128]bf16 @ W2[128,64] ----------------

__global__ __launch_bounds__(256) void k_lin2(
    const unsigned short* __restrict__ h1b,   // [N][128] bf16
    const float* __restrict__ W2,             // [128][64] fp32
    const float* __restrict__ asrc, const float* __restrict__ adst,
    unsigned short* __restrict__ hlin2b, float* __restrict__ es2, float* __restrict__ ed2, int N)
{
    int t = threadIdx.x, lane = t & 63, w = t >> 6;
    int vb = blockIdx.x * 64 + w * 16;
    if (vb >= N) return;
    int lo4 = lane & 15, hi4 = lane >> 4;

    int arow = vb + lo4; if (arow >= N) arow = N - 1;
    const unsigned short* ap = h1b + (size_t)arow*128 + hi4*8;
    bf16x8 a0 = *(const bf16x8*)(ap);
    bf16x8 a1 = *(const bf16x8*)(ap + 32);
    bf16x8 a2 = *(const bf16x8*)(ap + 64);
    bf16x8 a3 = *(const bf16x8*)(ap + 96);

    f32x4 acc[4];
    #pragma unroll
    for (int nt = 0; nt < 4; ++nt) acc[nt] = (f32x4){0.f, 0.f, 0.f, 0.f};

    #pragma unroll
    for (int nt = 0; nt < 4; ++nt){
        int cb = nt*16 + lo4;
        #pragma unroll
        for (int kt = 0; kt < 4; ++kt){
            const float* wp = W2 + (size_t)(kt*32 + hi4*8)*64 + cb;
            bf16x8 b;
            #pragma unroll
            for (int j = 0; j < 8; ++j) b[j] = (short)f2bf(wp[(size_t)j*64]);
            bf16x8 a = (kt==0) ? a0 : (kt==1) ? a1 : (kt==2) ? a2 : a3;
            acc[nt] = __builtin_amdgcn_mfma_f32_16x16x32_bf16(a, b, acc[nt], 0, 0, 0);
        }
    }

    float sa0 = asrc[lo4], sa1 = asrc[16+lo4], sa2 = asrc[32+lo4], sa3 = asrc[48+lo4];
    float sb0 = adst[lo4], sb1 = adst[16+lo4], sb2 = adst[32+lo4], sb3 = adst[48+lo4];

    #pragma unroll
    for (int reg = 0; reg < 4; ++reg){
        int nr = vb + hi4*4 + reg;
        bool ok = nr < N;
        float c0 = acc[0][reg], c1 = acc[1][reg], c2 = acc[2][reg], c3 = acc[3][reg];
        if (ok){
            unsigned short* hp = hlin2b + (size_t)nr*64 + lo4;
            hp[ 0] = f2bf(c0);
            hp[16] = f2bf(c1);
            hp[32] = f2bf(c2);
            hp[48] = f2bf(c3);
        }
        float ps0 = c0*sa0 + c1*sa1, ps1 = c2*sa2 + c3*sa3;
        float pd0 = c0*sb0 + c1*sb1, pd1 = c2*sb2 + c3*sb3;
        #pragma unroll
        for (int m = 8; m >= 1; m >>= 1){
            ps0 += __shfl_xor(ps0, m); ps1 += __shfl_xor(ps1, m);
            pd0 += __shfl_xor(pd0, m); pd1 += __shfl_xor(pd1, m);
        }
        if (ok && lo4 == 0){
            float2 e; e.x = ps0; e.y = ps1;
            float2 d; d.x = pd0; d.y = pd1;
            *(float2*)(es2 + (size_t)nr*2) = e;
            *(float2*)(ed2 + (size_t)nr*2) = d;
        }
    }
}

// ---------------- layer 2: fused single-pass attn+agg + head-mean + ELU + skip + LN ----------------

__global__ __launch_bounds__(256) void k_agg2(
    const unsigned short* __restrict__ hlin2b,   // [N][64] bf16
    const float* __restrict__ es2, const float* __restrict__ ed2,
    const int* __restrict__ row_ptr, const int* __restrict__ col,
    const float* __restrict__ x, const float* __restrict__ Wskip, const float* __restrict__ bskip,
    const float* __restrict__ b2, const float* __restrict__ g2, const float* __restrict__ be2,
    float* __restrict__ h2, int N)
{
    __shared__ float sp[4][2][68];
    int t = threadIdx.x, lane = t & 63, w = t >> 6;
    int v = blockIdx.x * 4 + w;
    if (v >= N) return;
    float2 edv = *(const float2*)(ed2 + (size_t)v*2);
    float2 esv = *(const float2*)(es2 + (size_t)v*2);
    int hsel = lane >> 5;
    float dsel = hsel ? edv.y : edv.x;
    float esel = hsel ? esv.y : esv.x;
    float pself = __expf(lrelu(esel + dsel));
    float acc = pself * __uint_as_float(((unsigned)hlin2b[(size_t)v*64 + lane]) << 16);
    float sum_p = pself;
    int beg = row_ptr[v], end = row_ptr[v+1];
    for (int base = beg; base < end; base += 64){
        int cnt = min(64, end - base);
        int sreg = 0;
        if (lane < cnt){
            sreg = col[base + lane];
            float2 q = *(const float2*)(es2 + (size_t)sreg*2);
            sp[w][0][lane] = __expf(lrelu(q.x + edv.x));
            sp[w][1][lane] = __expf(lrelu(q.y + edv.y));
        }
        asm volatile("s_waitcnt lgkmcnt(0)" ::: "memory");
        for (int jj = 0; jj < cnt; ++jj){
            int s = __builtin_amdgcn_readlane(sreg, jj);
            float p = sp[w][hsel][jj];
            unsigned short u = hlin2b[(size_t)s*64 + lane];
            sum_p += p;
            acc += p * __uint_as_float(((unsigned)u) << 16);
        }
    }
    acc /= (sum_p + 1e-16f);
    float other = __shfl(acc, lane ^ 32);
    if (lane < 32){
        float o = 0.5f * (acc + other) + b2[lane];
        o = eluf(o);
        float sk = x[(size_t)v*3]*Wskip[lane] + x[(size_t)v*3+1]*Wskip[32+lane]
                 + x[(size_t)v*3+2]*Wskip[64+lane] + bskip[lane];
        float z = o + sk;
        float su = z;
        #pragma unroll
        for (int k = 16; k >= 1; k >>= 1) su += __shfl_xor(su, k);
        float mean = su * (1.f/32.f);
        float d = z - mean;
        float vs = d*d;
        #pragma unroll
        for (int k = 16; k >= 1; k >>= 1) vs += __shfl_xor(vs, k);
        float rstd = rsqrtf(vs * (1.f/32.f) + LN_EPS);
        h2[(size_t)v*32 + lane] = d*rstd*g2[lane] + be2[lane];
    }
}

// ---------------- pooling: per-graph mean/max/std (batch sorted) + projection ----------------

__global__ __launch_bounds__(256) void k_pool(
    const float* __restrict__ h2, const int* __restrict__ batch,
    const float* __restrict__ Wp, const float* __restrict__ bp,
    float* __restrict__ out, int N)
{
    int g = blockIdx.x; int t = threadIdx.x;
    __shared__ int sBeg, sEnd;
    if (t == 0){
        int lo = 0, hi = N;
        while (lo < hi){ int mid = (lo+hi) >> 1; if (batch[mid] < g) lo = mid+1; else hi = mid; }
        sBeg = lo;
        lo = sBeg; hi = N;
        while (lo < hi){ int mid = (lo+hi) >> 1; if (batch[mid] < g+1) lo = mid+1; else hi = mid; }
        sEnd = lo;
    }
    __syncthreads();
    int beg = sBeg, end = sEnd;
    int ch = t & 31, grp = t >> 5;
    float sum = 0.f, sq = 0.f, mx = -INFINITY;
    for (int i = beg + grp; i < end; i += 8){
        float val = h2[(size_t)i*32 + ch];
        sum += val; sq += val*val; mx = fmaxf(mx, val);
    }
    __shared__ float lsum[256], lsq[256], lmx[256];
    lsum[t] = sum; lsq[t] = sq; lmx[t] = mx;
    __syncthreads();
    for (int s = 4; s >= 1; s >>= 1){
        if (grp < s){
            lsum[t] += lsum[t + s*32];
            lsq [t] += lsq [t + s*32];
            lmx [t]  = fmaxf(lmx[t], lmx[t + s*32]);
        }
        __syncthreads();
    }
    __shared__ float feat[96];
    if (t < 32){
        float cnt = fmaxf((float)(end - beg), 1.f);
        float mean = lsum[t] / cnt;
        float var  = lsq[t] / cnt - mean*mean;
        feat[t]      = mean;
        feat[32 + t] = lmx[t];
        feat[64 + t] = sqrtf(fmaxf(var, 0.f));
    }
    __syncthreads();
    if (t < 48){
        float acc = bp[t];
        #pragma unroll 8
        for (int k = 0; k < 96; ++k) acc += feat[k] * Wp[k*48 + t];
        out[(size_t)g*48 + t] = acc;
    }
}

// ---------------- launcher ----------------

extern "C" void kernel_launch(void* const* d_in, const int* in_sizes, int n_in,
                              void* d_out, int out_size, void* d_ws, size_t ws_size,
                              hipStream_t stream)
{
    const float* x     = (const float*)d_in[0];
    const int*   ei    = (const int*)  d_in[1];
    const int*   batch = (const int*)  d_in[2];
    const float* W1    = (const float*)d_in[3];
    const float* as1   = (const float*)d_in[4];
    const float* ad1   = (const float*)d_in[5];
    const float* b1    = (const float*)d_in[6];
    const float* W2    = (const float*)d_in[7];
    const float* as2   = (const float*)d_in[8];
    const float* ad2   = (const float*)d_in[9];
    const float* b2    = (const float*)d_in[10];
    const float* Wskip = (const float*)d_in[11];
    const float* bskip = (const float*)d_in[12];
    const float* g1    = (const float*)d_in[13];
    const float* be1   = (const float*)d_in[14];
    const float* g2    = (const float*)d_in[15];
    const float* be2   = (const float*)d_in[16];
    const float* Wp    = (const float*)d_in[17];
    const float* bp    = (const float*)d_in[18];

    int N = in_sizes[0] / 3;
    int E = in_sizes[1] / 2;
    int B = out_size / 48;
    const int* src = ei;
    const int* dst = ei + E;
    int NBUK = (N + 63) / 64;              // 1563 (<= 2048 LDS counters)
    int chunk = (E + NWG - 1) / NWG;
    int M = NBUK * NWG;                    // 75024 histogram entries

    char* w = (char*)d_ws;
    auto alloc = [&](size_t bytes) -> char* {
        char* p = w; w += (bytes + 255) & ~(size_t)255; return p;
    };
    int*   row_ptr = (int*)  alloc((size_t)(N+1)*4);
    int*   hist    = (int*)  alloc((size_t)M*4);
    int*   partial = (int*)  alloc(4*1024);
    int*   col     = (int*)  alloc((size_t)E*4);
    unsigned* hlinb= (unsigned*)alloc((size_t)N*64*4); // L1: bf16x2[N][64]; L2 reuses as u16[N][64]
    float* es      = (float*)alloc((size_t)N*4*4);
    float* ed      = (float*)alloc((size_t)N*4*4);
    unsigned* h1b  = (unsigned*)alloc((size_t)N*64*4); // bf16[N][128]
    float* h2      = (float*)alloc((size_t)N*32*4);
    unsigned* ebuf = (unsigned*)h2;                    // alias: ebuf dead before agg2 writes h2
    (void)ws_size;

    int mb  = (M + 255) / 256;             // 294 <= 512: single-block partial scan ok
    int nb  = (N + 3) / 4;
    int nb2 = (N + 63) / 64;

    k_hist        <<<NWG, 512, 0, stream>>>(dst, hist, E, NBUK, chunk);
    k_chunk_sum   <<<mb, 256, 0, stream>>>(hist, partial, M);
    k_scan_partial<<<1, 512, 0, stream>>>(partial, mb);
    k_scan_apply  <<<mb, 256, 0, stream>>>(hist, partial, M);
    k_pscatter    <<<NWG, 512, 0, stream>>>(src, dst, hist, ebuf, E, NBUK, chunk);
    k_bfill       <<<(NBUK + 3) / 4, 256, 0, stream>>>(ebuf, hist, row_ptr, col, N, NBUK, E);

    k_lin1 <<<nb, 256, 0, stream>>>(x, W1, as1, ad1, hlinb, es, ed, N);
    k_agg1 <<<nb, 256, 0, stream>>>(hlinb, es, ed, row_ptr, col, b1, g1, be1, h1b, N);
    k_lin2 <<<nb2, 256, 0, stream>>>((const unsigned short*)h1b, W2, as2, ad2,
                                     (unsigned short*)hlinb, es, ed, N);
    k_agg2 <<<nb, 256, 0, stream>>>((unsigned short*)hlinb, es, ed, row_ptr, col,
                                    x, Wskip, bskip, b2, g2, be2, h2, N);
    k_pool <<<B, 256, 0, stream>>>(h2, batch, Wp, bp, (float*)d_out, N);
}

// Round 6
// 348.397 us; speedup vs baseline: 2.3024x; 1.1158x over previous
//
#include <hip/hip_runtime.h>
#include <math.h>

#define NEG_SLOPE 0.2f
#define LN_EPS 1e-5f
#define NWG 48          // scatter workgroups; hist = [NB][NWG]

typedef __attribute__((ext_vector_type(8))) short bf16x8;
typedef __attribute__((ext_vector_type(4))) float f32x4;

__device__ __forceinline__ float lrelu(float v){ return v > 0.f ? v : NEG_SLOPE * v; }
__device__ __forceinline__ float eluf (float v){ return v > 0.f ? v : expm1f(v); }

__device__ __forceinline__ unsigned short f2bf(float f){
    unsigned x = __float_as_uint(f);
    unsigned r = (x + 0x7fffu + ((x >> 16) & 1u)) >> 16;   // round-nearest-even
    return (unsigned short)r;
}
__device__ __forceinline__ float bf_lo(unsigned u){ return __uint_as_float(u << 16); }
__device__ __forceinline__ float bf_hi(unsigned u){ return __uint_as_float(u & 0xffff0000u); }

// ---------------- bucketed CSR build, atomic-free scatter ----------------

__global__ __launch_bounds__(512) void k_hist(
    const int* __restrict__ dst, int* __restrict__ hist, int E, int NB, int chunk)
{
    __shared__ int cnt[2048];
    int t = threadIdx.x, w = blockIdx.x;
    for (int i = t; i < NB; i += 512) cnt[i] = 0;
    __syncthreads();
    int e0 = w * chunk, e1 = min(E, e0 + chunk);
    for (int e = e0 + t; e < e1; e += 512)
        atomicAdd(&cnt[dst[e] >> 6], 1);
    __syncthreads();
    for (int i = t; i < NB; i += 512)
        hist[i * NWG + w] = cnt[i];
}

__global__ void k_chunk_sum(const int* __restrict__ data, int* __restrict__ partial, int M){
    __shared__ int lds[256];
    int t = threadIdx.x;
    int v = blockIdx.x * 256 + t;
    lds[t] = (v < M) ? data[v] : 0;
    __syncthreads();
    for (int s = 128; s > 0; s >>= 1){
        if (t < s) lds[t] += lds[t + s];
        __syncthreads();
    }
    if (t == 0) partial[blockIdx.x] = lds[0];
}

__global__ void k_scan_partial(int* __restrict__ partial, int n){
    __shared__ int lds[512];
    int t = threadIdx.x;
    int x = (t < n) ? partial[t] : 0;
    lds[t] = x;
    __syncthreads();
    for (int s = 1; s < 512; s <<= 1){
        int a = (t >= s) ? lds[t - s] : 0;
        __syncthreads();
        lds[t] += a;
        __syncthreads();
    }
    if (t < n) partial[t] = lds[t] - x;   // exclusive
}

__global__ void k_scan_apply(int* __restrict__ data, const int* __restrict__ partial, int M){
    __shared__ int lds[256];
    int t = threadIdx.x;
    int v = blockIdx.x * 256 + t;
    int x = (v < M) ? data[v] : 0;
    lds[t] = x;
    __syncthreads();
    for (int s = 1; s < 256; s <<= 1){
        int a = (t >= s) ? lds[t - s] : 0;
        __syncthreads();
        lds[t] += a;
        __syncthreads();
    }
    if (v < M) data[v] = partial[blockIdx.x] + lds[t] - x;   // exclusive
}

__global__ __launch_bounds__(512) void k_pscatter(
    const int* __restrict__ src, const int* __restrict__ dst,
    const int* __restrict__ shist, unsigned* __restrict__ ebuf, int E, int NB, int chunk)
{
    __shared__ int cur[2048];
    int t = threadIdx.x, w = blockIdx.x;
    for (int i = t; i < NB; i += 512) cur[i] = shist[i * NWG + w];
    __syncthreads();
    int e0 = w * chunk, e1 = min(E, e0 + chunk);
    for (int e = e0 + t; e < e1; e += 512){
        int d = dst[e];
        int pos = atomicAdd(&cur[d >> 6], 1);
        ebuf[pos] = ((unsigned)(d & 63) << 26) | (unsigned)src[e];
    }
}

// one wave per bucket: local degree count -> wave-scan -> row_ptr + LDS-cursor fill
__global__ __launch_bounds__(256) void k_bfill(
    const unsigned* __restrict__ ebuf, const int* __restrict__ shist,
    int* __restrict__ row_ptr, int* __restrict__ col, int N, int NB, int E)
{
    __shared__ int scnt[4][64];
    int t = threadIdx.x, lane = t & 63, w = t >> 6;
    int b = blockIdx.x * 4 + w;
    bool act = b < NB;
    if (t == 0 && blockIdx.x == 0) row_ptr[N] = E;
    scnt[w][lane] = 0;
    __syncthreads();
    int ebeg = 0, eend = 0;
    if (act){
        ebeg = shist[b * NWG];
        eend = (b + 1 < NB) ? shist[(b + 1) * NWG] : E;
    }
    for (int j = ebeg + lane; j < eend; j += 64)
        atomicAdd(&scnt[w][ebuf[j] >> 26], 1);
    __syncthreads();
    int deg = scnt[w][lane];
    int incl = deg;
    #pragma unroll
    for (int k = 1; k < 64; k <<= 1){
        int up = __shfl_up(incl, k);
        if (lane >= k) incl += up;
    }
    int excl = incl - deg;
    int base = act ? ebeg : 0;
    int v = b * 64 + lane;
    if (act && v < N) row_ptr[v] = base + excl;
    __syncthreads();
    scnt[w][lane] = base + excl;
    __syncthreads();
    for (int j = ebeg + lane; j < eend; j += 64){
        unsigned u = ebuf[j];
        int pos = atomicAdd(&scnt[w][u >> 26], 1);
        col[pos] = (int)(u & 0x03FFFFFFu);
    }
}

// ---------------- layer 1 attention logits: es/ed only (h recomputed in agg1) ----------------

__global__ __launch_bounds__(256) void k_lin1(
    const float* __restrict__ x, const float* __restrict__ W1,
    const float* __restrict__ asrc, const float* __restrict__ adst,
    float* __restrict__ es, float* __restrict__ ed, int N)
{
    __shared__ float sW[384], sA[128], sB[128];
    int t = threadIdx.x;
    for (int i = t; i < 384; i += 256) sW[i] = W1[i];
    for (int i = t; i < 128; i += 256){ sA[i] = asrc[i]; sB[i] = adst[i]; }
    __syncthreads();
    int lane = t & 63;
    int v = blockIdx.x * 4 + (t >> 6);
    if (v >= N) return;
    float x0 = x[(size_t)v*3], x1 = x[(size_t)v*3+1], x2 = x[(size_t)v*3+2];
    int c = lane * 2;
    float h0 = x0*sW[c  ] + x1*sW[128+c  ] + x2*sW[256+c  ];
    float h1 = x0*sW[c+1] + x1*sW[128+c+1] + x2*sW[256+c+1];
    int hsel = lane >> 4;
    float ts = h0*sA[c] + h1*sA[c+1];
    float td = h0*sB[c] + h1*sB[c+1];
    #pragma unroll
    for (int m = 8; m >= 1; m >>= 1){
        ts += __shfl_xor(ts, m); td += __shfl_xor(td, m);
    }
    if ((lane & 15) == 0){
        es[(size_t)v*4 + hsel] = ts;
        ed[(size_t)v*4 + hsel] = td;
    }
}

// ---------------- layer 1: fused attn+agg, h recomputed on the fly (x gather = 12 B/edge) ----------------
// wave = 4 edge slots x 16 lanes; lane handles channels l*8..l*8+7 (head l>>2)

__global__ __launch_bounds__(256) void k_agg1(
    const float* __restrict__ x, const float* __restrict__ W1,
    const float* __restrict__ es, const float* __restrict__ ed,
    const int* __restrict__ row_ptr, const int* __restrict__ col,
    const float* __restrict__ b1, const float* __restrict__ g1, const float* __restrict__ be1,
    unsigned* __restrict__ h1b, int N)
{
    __shared__ float sp[4][4][68];
    int t = threadIdx.x, lane = t & 63, w = t >> 6;
    int v = blockIdx.x * 4 + w;
    if (v >= N) return;
    int g = lane >> 4, l = lane & 15;
    int c0 = l * 8;
    int hsel = l >> 2;
    float4 wA0 = *(const float4*)(W1 + c0),       wA1 = *(const float4*)(W1 + c0 + 4);
    float4 wB0 = *(const float4*)(W1 + 128 + c0), wB1 = *(const float4*)(W1 + 128 + c0 + 4);
    float4 wC0 = *(const float4*)(W1 + 256 + c0), wC1 = *(const float4*)(W1 + 256 + c0 + 4);
    float w0[8] = {wA0.x,wA0.y,wA0.z,wA0.w, wA1.x,wA1.y,wA1.z,wA1.w};
    float w1[8] = {wB0.x,wB0.y,wB0.z,wB0.w, wB1.x,wB1.y,wB1.z,wB1.w};
    float w2[8] = {wC0.x,wC0.y,wC0.z,wC0.w, wC1.x,wC1.y,wC1.z,wC1.w};

    float4 edv = *(const float4*)(ed + (size_t)v*4);
    float4 esv = *(const float4*)(es + (size_t)v*4);
    float eh = (hsel==0?esv.x:hsel==1?esv.y:hsel==2?esv.z:esv.w)
             + (hsel==0?edv.x:hsel==1?edv.y:hsel==2?edv.z:edv.w);
    float pself = (g == 0) ? __expf(lrelu(eh)) : 0.f;   // self counted once across slots
    float xa = x[(size_t)v*3], xb = x[(size_t)v*3+1], xc = x[(size_t)v*3+2];
    float acc[8];
    {
        float pa = pself*xa, pb = pself*xb, pc = pself*xc;
        #pragma unroll
        for (int j = 0; j < 8; ++j) acc[j] = pa*w0[j] + pb*w1[j] + pc*w2[j];
    }
    float sum_p = pself;

    int beg = row_ptr[v], end = row_ptr[v+1];
    for (int base = beg; base < end; base += 64){
        int cnt = min(64, end - base);
        int sreg = 0;
        if (lane < cnt){
            sreg = col[base + lane];
            float4 q = *(const float4*)(es + (size_t)sreg*4);
            sp[w][0][lane] = __expf(lrelu(q.x + edv.x));
            sp[w][1][lane] = __expf(lrelu(q.y + edv.y));
            sp[w][2][lane] = __expf(lrelu(q.z + edv.z));
            sp[w][3][lane] = __expf(lrelu(q.w + edv.w));
        }
        asm volatile("s_waitcnt lgkmcnt(0)" ::: "memory");
        for (int i = 0; i < cnt; i += 4){
            int e = i + g;
            bool val = e < cnt;
            int s = __shfl(sreg, e);
            if (!val) s = v;
            float p = val ? sp[w][hsel][e] : 0.f;
            const float* xp = x + (size_t)s*3;
            float ya = xp[0], yb = xp[1], yc = xp[2];
            sum_p += p;
            float pa = p*ya, pb = p*yb, pc = p*yc;
            #pragma unroll
            for (int j = 0; j < 8; ++j) acc[j] += pa*w0[j] + pb*w1[j] + pc*w2[j];
        }
    }
    // combine the 4 edge slots
    #pragma unroll
    for (int j = 0; j < 8; ++j){
        acc[j] += __shfl_xor(acc[j], 16);
        acc[j] += __shfl_xor(acc[j], 32);
    }
    sum_p += __shfl_xor(sum_p, 16);
    sum_p += __shfl_xor(sum_p, 32);
    float inv = 1.f / (sum_p + 1e-16f);

    float4 bb0 = *(const float4*)(b1 + c0), bb1 = *(const float4*)(b1 + c0 + 4);
    float bv[8] = {bb0.x,bb0.y,bb0.z,bb0.w, bb1.x,bb1.y,bb1.z,bb1.w};
    float o[8];
    #pragma unroll
    for (int j = 0; j < 8; ++j) o[j] = eluf(acc[j]*inv + bv[j]);
    float su = 0.f;
    #pragma unroll
    for (int j = 0; j < 8; ++j) su += o[j];
    su += __shfl_xor(su,1); su += __shfl_xor(su,2); su += __shfl_xor(su,4); su += __shfl_xor(su,8);
    float mean = su * (1.f/128.f);
    float vs = 0.f;
    #pragma unroll
    for (int j = 0; j < 8; ++j){ float d = o[j]-mean; vs += d*d; }
    vs += __shfl_xor(vs,1); vs += __shfl_xor(vs,2); vs += __shfl_xor(vs,4); vs += __shfl_xor(vs,8);
    float rstd = rsqrtf(vs * (1.f/128.f) + LN_EPS);
    if (g == 0){
        float4 gg0 = *(const float4*)(g1 + c0),  gg1 = *(const float4*)(g1 + c0 + 4);
        float4 ee0 = *(const float4*)(be1 + c0), ee1 = *(const float4*)(be1 + c0 + 4);
        float gv[8] = {gg0.x,gg0.y,gg0.z,gg0.w, gg1.x,gg1.y,gg1.z,gg1.w};
        float ev[8] = {ee0.x,ee0.y,ee0.z,ee0.w, ee1.x,ee1.y,ee1.z,ee1.w};
        unsigned uo[4];
        #pragma unroll
        for (int j = 0; j < 4; ++j){
            float ra = (o[2*j  ]-mean)*rstd*gv[2*j  ] + ev[2*j  ];
            float rb = (o[2*j+1]-mean)*rstd*gv[2*j+1] + ev[2*j+1];
            uo[j] = (unsigned)f2bf(ra) | ((unsigned)f2bf(rb) << 16);
        }
        uint4 pk; pk.x = uo[0]; pk.y = uo[1]; pk.z = uo[2]; pk.w = uo[3];
        *(uint4*)(h1b + (size_t)v*64 + l*4) = pk;
    }
}

// ---------------- layer 2 linear via MFMA: h1b[N,128]bf16 @ W2[128,64] ----------------

__global__ __launch_bounds__(256) void k_lin2(
    const unsigned short* __restrict__ h1b,   // [N][128] bf16
    const float* __restrict__ W2,             // [128][64] fp32
    const float* __restrict__ asrc, const float* __restrict__ adst,
    unsigned short* __restrict__ hlin2b, float* __restrict__ es2, float* __restrict__ ed2, int N)
{
    int t = threadIdx.x, lane = t & 63, w = t >> 6;
    int vb = blockIdx.x * 64 + w * 16;
    if (vb >= N) return;
    int lo4 = lane & 15, hi4 = lane >> 4;

    int arow = vb + lo4; if (arow >= N) arow = N - 1;
    const unsigned short* ap = h1b + (size_t)arow*128 + hi4*8;
    bf16x8 a0 = *(const bf16x8*)(ap);
    bf16x8 a1 = *(const bf16x8*)(ap + 32);
    bf16x8 a2 = *(const bf16x8*)(ap + 64);
    bf16x8 a3 = *(const bf16x8*)(ap + 96);

    f32x4 acc[4];
    #pragma unroll
    for (int nt = 0; nt < 4; ++nt) acc[nt] = (f32x4){0.f, 0.f, 0.f, 0.f};

    #pragma unroll
    for (int nt = 0; nt < 4; ++nt){
        int cb = nt*16 + lo4;
        #pragma unroll
        for (int kt = 0; kt < 4; ++kt){
            const float* wp = W2 + (size_t)(kt*32 + hi4*8)*64 + cb;
            bf16x8 b;
            #pragma unroll
            for (int j = 0; j < 8; ++j) b[j] = (short)f2bf(wp[(size_t)j*64]);
            bf16x8 a = (kt==0) ? a0 : (kt==1) ? a1 : (kt==2) ? a2 : a3;
            acc[nt] = __builtin_amdgcn_mfma_f32_16x16x32_bf16(a, b, acc[nt], 0, 0, 0);
        }
    }

    float sa0 = asrc[lo4], sa1 = asrc[16+lo4], sa2 = asrc[32+lo4], sa3 = asrc[48+lo4];
    float sb0 = adst[lo4], sb1 = adst[16+lo4], sb2 = adst[32+lo4], sb3 = adst[48+lo4];

    #pragma unroll
    for (int reg = 0; reg < 4; ++reg){
        int nr = vb + hi4*4 + reg;
        bool ok = nr < N;
        float c0 = acc[0][reg], c1 = acc[1][reg], c2 = acc[2][reg], c3 = acc[3][reg];
        if (ok){
            unsigned short* hp = hlin2b + (size_t)nr*64 + lo4;
            hp[ 0] = f2bf(c0);
            hp[16] = f2bf(c1);
            hp[32] = f2bf(c2);
            hp[48] = f2bf(c3);
        }
        float ps0 = c0*sa0 + c1*sa1, ps1 = c2*sa2 + c3*sa3;
        float pd0 = c0*sb0 + c1*sb1, pd1 = c2*sb2 + c3*sb3;
        #pragma unroll
        for (int m = 8; m >= 1; m >>= 1){
            ps0 += __shfl_xor(ps0, m); ps1 += __shfl_xor(ps1, m);
            pd0 += __shfl_xor(pd0, m); pd1 += __shfl_xor(pd1, m);
        }
        if (ok && lo4 == 0){
            float2 e; e.x = ps0; e.y = ps1;
            float2 d; d.x = pd0; d.y = pd1;
            *(float2*)(es2 + (size_t)nr*2) = e;
            *(float2*)(ed2 + (size_t)nr*2) = d;
        }
    }
}

// ---------------- layer 2: fused attn+agg (EPG=4) + head-mean + ELU + skip + LN ----------------
// wave = 4 edge slots x 16 lanes; lane handles channels l*4..l*4+3 (head l>>3)

__global__ __launch_bounds__(256) void k_agg2(
    const unsigned* __restrict__ h2b,          // [N][32] u32 = bf16[N][64]
    const float* __restrict__ es2, const float* __restrict__ ed2,
    const int* __restrict__ row_ptr, const int* __restrict__ col,
    const float* __restrict__ x, const float* __restrict__ Wskip, const float* __restrict__ bskip,
    const float* __restrict__ b2, const float* __restrict__ g2, const float* __restrict__ be2,
    float* __restrict__ h2, int N)
{
    __shared__ float sp[4][2][68];
    int t = threadIdx.x, lane = t & 63, w = t >> 6;
    int v = blockIdx.x * 4 + w;
    if (v >= N) return;
    int g = lane >> 4, l = lane & 15;
    int hsel = l >> 3;
    float2 edv = *(const float2*)(ed2 + (size_t)v*2);
    float2 esv = *(const float2*)(es2 + (size_t)v*2);
    float eh = (hsel ? esv.y : esv.x) + (hsel ? edv.y : edv.x);
    float pself = (g == 0) ? __expf(lrelu(eh)) : 0.f;
    uint2 us = *(const uint2*)(h2b + (size_t)v*32 + l*2);
    float acc[4];
    acc[0] = pself * bf_lo(us.x);
    acc[1] = pself * bf_hi(us.x);
    acc[2] = pself * bf_lo(us.y);
    acc[3] = pself * bf_hi(us.y);
    float sum_p = pself;

    int beg = row_ptr[v], end = row_ptr[v+1];
    for (int base = beg; base < end; base += 64){
        int cnt = min(64, end - base);
        int sreg = 0;
        if (lane < cnt){
            sreg = col[base + lane];
            float2 q = *(const float2*)(es2 + (size_t)sreg*2);
            sp[w][0][lane] = __expf(lrelu(q.x + edv.x));
            sp[w][1][lane] = __expf(lrelu(q.y + edv.y));
        }
        asm volatile("s_waitcnt lgkmcnt(0)" ::: "memory");
        for (int i = 0; i < cnt; i += 4){
            int e = i + g;
            bool val = e < cnt;
            int s = __shfl(sreg, e);
            if (!val) s = v;
            float p = val ? sp[w][hsel][e] : 0.f;
            uint2 u = *(const uint2*)(h2b + (size_t)s*32 + l*2);
            sum_p += p;
            acc[0] += p * bf_lo(u.x);
            acc[1] += p * bf_hi(u.x);
            acc[2] += p * bf_lo(u.y);
            acc[3] += p * bf_hi(u.y);
        }
    }
    #pragma unroll
    for (int j = 0; j < 4; ++j){
        acc[j] += __shfl_xor(acc[j], 16);
        acc[j] += __shfl_xor(acc[j], 32);
    }
    sum_p += __shfl_xor(sum_p, 16);
    sum_p += __shfl_xor(sum_p, 32);
    float inv = 1.f / (sum_p + 1e-16f);
    #pragma unroll
    for (int j = 0; j < 4; ++j) acc[j] *= inv;
    // head mean: lane l pairs with l^8 (channels c and c+32)
    float xa = x[(size_t)v*3], xb = x[(size_t)v*3+1], xc = x[(size_t)v*3+2];
    int cc = (l & 7) * 4;
    float z[4];
    #pragma unroll
    for (int j = 0; j < 4; ++j){
        float other = __shfl_xor(acc[j], 8);
        float o = eluf(0.5f*(acc[j] + other) + b2[cc+j]);
        float sk = xa*Wskip[cc+j] + xb*Wskip[32+cc+j] + xc*Wskip[64+cc+j] + bskip[cc+j];
        z[j] = o + sk;
    }
    float su = z[0]+z[1]+z[2]+z[3];
    su += __shfl_xor(su,1); su += __shfl_xor(su,2); su += __shfl_xor(su,4);
    float mean = su * (1.f/32.f);
    float vs = 0.f;
    #pragma unroll
    for (int j = 0; j < 4; ++j){ float d = z[j]-mean; vs += d*d; }
    vs += __shfl_xor(vs,1); vs += __shfl_xor(vs,2); vs += __shfl_xor(vs,4);
    float rstd = rsqrtf(vs * (1.f/32.f) + LN_EPS);
    if (g == 0 && l < 8){
        float4 r;
        r.x = (z[0]-mean)*rstd*g2[cc  ] + be2[cc  ];
        r.y = (z[1]-mean)*rstd*g2[cc+1] + be2[cc+1];
        r.z = (z[2]-mean)*rstd*g2[cc+2] + be2[cc+2];
        r.w = (z[3]-mean)*rstd*g2[cc+3] + be2[cc+3];
        *(float4*)(h2 + (size_t)v*32 + cc) = r;
    }
}

// ---------------- pooling: per-graph mean/max/std (batch sorted) + projection ----------------

__global__ __launch_bounds__(256) void k_pool(
    const float* __restrict__ h2, const int* __restrict__ batch,
    const float* __restrict__ Wp, const float* __restrict__ bp,
    float* __restrict__ out, int N)
{
    int g = blockIdx.x; int t = threadIdx.x;
    __shared__ int sBeg, sEnd;
    if (t == 0){
        int lo = 0, hi = N;
        while (lo < hi){ int mid = (lo+hi) >> 1; if (batch[mid] < g) lo = mid+1; else hi = mid; }
        sBeg = lo;
        lo = sBeg; hi = N;
        while (lo < hi){ int mid = (lo+hi) >> 1; if (batch[mid] < g+1) lo = mid+1; else hi = mid; }
        sEnd = lo;
    }
    __syncthreads();
    int beg = sBeg, end = sEnd;
    int ch = t & 31, grp = t >> 5;
    float sum = 0.f, sq = 0.f, mx = -INFINITY;
    for (int i = beg + grp; i < end; i += 8){
        float val = h2[(size_t)i*32 + ch];
        sum += val; sq += val*val; mx = fmaxf(mx, val);
    }
    __shared__ float lsum[256], lsq[256], lmx[256];
    lsum[t] = sum; lsq[t] = sq; lmx[t] = mx;
    __syncthreads();
    for (int s = 4; s >= 1; s >>= 1){
        if (grp < s){
            lsum[t] += lsum[t + s*32];
            lsq [t] += lsq [t + s*32];
            lmx [t]  = fmaxf(lmx[t], lmx[t + s*32]);
        }
        __syncthreads();
    }
    __shared__ float feat[96];
    if (t < 32){
        float cnt = fmaxf((float)(end - beg), 1.f);
        float mean = lsum[t] / cnt;
        float var  = lsq[t] / cnt - mean*mean;
        feat[t]      = mean;
        feat[32 + t] = lmx[t];
        feat[64 + t] = sqrtf(fmaxf(var, 0.f));
    }
    __syncthreads();
    if (t < 48){
        float acc = bp[t];
        #pragma unroll 8
        for (int k = 0; k < 96; ++k) acc += feat[k] * Wp[k*48 + t];
        out[(size_t)g*48 + t] = acc;
    }
}

// ---------------- launcher ----------------

extern "C" void kernel_launch(void* const* d_in, const int* in_sizes, int n_in,
                              void* d_out, int out_size, void* d_ws, size_t ws_size,
                              hipStream_t stream)
{
    const float* x     = (const float*)d_in[0];
    const int*   ei    = (const int*)  d_in[1];
    const int*   batch = (const int*)  d_in[2];
    const float* W1    = (const float*)d_in[3];
    const float* as1   = (const float*)d_in[4];
    const float* ad1   = (const float*)d_in[5];
    const float* b1    = (const float*)d_in[6];
    const float* W2    = (const float*)d_in[7];
    const float* as2   = (const float*)d_in[8];
    const float* ad2   = (const float*)d_in[9];
    const float* b2    = (const float*)d_in[10];
    const float* Wskip = (const float*)d_in[11];
    const float* bskip = (const float*)d_in[12];
    const float* g1    = (const float*)d_in[13];
    const float* be1   = (const float*)d_in[14];
    const float* g2    = (const float*)d_in[15];
    const float* be2   = (const float*)d_in[16];
    const float* Wp    = (const float*)d_in[17];
    const float* bp    = (const float*)d_in[18];

    int N = in_sizes[0] / 3;
    int E = in_sizes[1] / 2;
    int B = out_size / 48;
    const int* src = ei;
    const int* dst = ei + E;
    int NBUK = (N + 63) / 64;
    int chunk = (E + NWG - 1) / NWG;
    int M = NBUK * NWG;

    char* w = (char*)d_ws;
    auto alloc = [&](size_t bytes) -> char* {
        char* p = w; w += (bytes + 255) & ~(size_t)255; return p;
    };
    int*   row_ptr = (int*)  alloc((size_t)(N+1)*4);
    int*   hist    = (int*)  alloc((size_t)M*4);
    int*   partial = (int*)  alloc(4*1024);
    int*   col     = (int*)  alloc((size_t)E*4);
    unsigned* h2b  = (unsigned*)alloc((size_t)N*32*4); // bf16[N][64] layer2 staging
    float* es      = (float*)alloc((size_t)N*4*4);
    float* ed      = (float*)alloc((size_t)N*4*4);
    unsigned* h1b  = (unsigned*)alloc((size_t)N*64*4); // bf16[N][128]
    float* h2      = (float*)alloc((size_t)N*32*4);
    unsigned* ebuf = (unsigned*)h2;                    // alias: ebuf dead before agg2 writes h2
    (void)ws_size;

    int mb  = (M + 255) / 256;
    int nb  = (N + 3) / 4;
    int nb2 = (N + 63) / 64;

    k_hist        <<<NWG, 512, 0, stream>>>(dst, hist, E, NBUK, chunk);
    k_chunk_sum   <<<mb, 256, 0, stream>>>(hist, partial, M);
    k_scan_partial<<<1, 512, 0, stream>>>(partial, mb);
    k_scan_apply  <<<mb, 256, 0, stream>>>(hist, partial, M);
    k_pscatter    <<<NWG, 512, 0, stream>>>(src, dst, hist, ebuf, E, NBUK, chunk);
    k_bfill       <<<(NBUK + 3) / 4, 256, 0, stream>>>(ebuf, hist, row_ptr, col, N, NBUK, E);

    k_lin1 <<<nb, 256, 0, stream>>>(x, W1, as1, ad1, es, ed, N);
    k_agg1 <<<nb, 256, 0, stream>>>(x, W1, es, ed, row_ptr, col, b1, g1, be1, h1b, N);
    k_lin2 <<<nb2, 256, 0, stream>>>((const unsigned short*)h1b, W2, as2, ad2,
                                     (unsigned short*)h2b, es, ed, N);
    k_agg2 <<<nb, 256, 0, stream>>>(h2b, es, ed, row_ptr, col,
                                    x, Wskip, bskip, b2, g2, be2, h2, N);
    k_pool <<<B, 256, 0, stream>>>(h2, batch, Wp, bp, (float*)d_out, N);
}